// Round 1
// baseline (391.254 us; speedup 1.0000x reference)
//
#include <hip/hip_runtime.h>
#include <cstdint>
#include <cstddef>

// Model dims
#define VOCABSZ 400001
#define Hn 100      // hidden
#define Tn 25       // timesteps
#define Bn 512      // batch
#define FCn 128
#define Rr 2        // rows (batch elems) per block
#define NBLK (Bn / Rr)   // 256 blocks -> all 256 CUs
#define NTHR 1024        // 16 waves: waves 0-6 = layer1, waves 8-14 = layer2

typedef _Float16 half2_t __attribute__((ext_vector_type(2)));

__device__ __forceinline__ half2_t h2bits(unsigned v) {
    union { unsigned u; half2_t h; } x; x.u = v; return x.h;
}
__device__ __forceinline__ float fdot2f(half2_t a, half2_t b, float c) {
    return __builtin_amdgcn_fdot2(a, b, c, false);   // v_dot2_f32_f16
}
__device__ __forceinline__ float sigm(float x) {
    return __fdividef(1.0f, 1.0f + __expf(-x));
}
__device__ __forceinline__ float tanh_fast(float x) {
    float e = __expf(2.0f * x);
    return __fdividef(e - 1.0f, e + 1.0f);
}

// ---------------------------------------------------------------------------
// Prep: repack k1,k2 (fp32 [200][400], columns c = g*100+u, gates i,j,f,o)
// into fp16 chunk layout WP[l][kq][o] (uint4), o = 4u+g owning column c.
// Chunk kq covers k = 8kq..8kq+7; dword j = fp16 pair (k=8kq+2j, 8kq+2j+1).
// Matches the x-side layout: LDS xh row read as uint4 at chunk kq.
// ---------------------------------------------------------------------------
__global__ void prep_weights(const float* __restrict__ k1,
                             const float* __restrict__ k2,
                             uint4* __restrict__ WP) {
    int t = blockIdx.x * blockDim.x + threadIdx.x;
    if (t >= 2 * 25 * 400) return;
    int l   = t / 10000;
    int rem = t % 10000;
    int kq  = rem / 400;
    int o   = rem % 400;
    int u = o >> 2, g = o & 3;
    int c = g * 100 + u;
    const float* K = l ? k2 : k1;
    union { unsigned u32; half2_t h; } d[4];
    #pragma unroll
    for (int j = 0; j < 4; j++) {
        int k0 = 8 * kq + 2 * j;
        d[j].h.x = (_Float16)K[(k0    ) * 400 + c];
        d[j].h.y = (_Float16)K[(k0 + 1) * 400 + c];
    }
    uint4 v; v.x = d[0].u32; v.y = d[1].u32; v.z = d[2].u32; v.w = d[3].u32;
    WP[t] = v;
}

// Gate exchange within the quad (o = 4u+g) + LSTM cell update.
// All 4 lanes of the quad end up with the same c,h (redundant, cheap).
__device__ __forceinline__ float lstm_update(float z, int g, float& cst) {
    float t1 = __shfl_xor(z, 1);
    float t2 = __shfl_xor(z, 2);
    float t3 = __shfl_xor(t1, 2);
    bool g0 = (g & 1) != 0, g1 = (g & 2) != 0;
    float vi = g1 ? (g0 ? t3 : t2) : (g0 ? t1 : z);
    float vj = g1 ? (g0 ? t2 : t3) : (g0 ? z  : t1);
    float vf = g1 ? (g0 ? t1 : z ) : (g0 ? t3 : t2);
    float vo = g1 ? (g0 ? z  : t1) : (g0 ? t2 : t3);
    cst = cst * sigm(vf + 1.0f) + sigm(vi) * tanh_fast(vj);   // forget_bias=1
    return tanh_fast(cst) * sigm(vo);
}

// GEMV for both rows of this block's batch pair.  Weights come from this
// thread's register file (w[25], one layer only); x/h vectors are read from
// LDS with wave-uniform ds_read_b128 (all lanes same address -> broadcast,
// conflict-free).  No readlane, no full-exec requirement.
__device__ __forceinline__ void gemv_ds(const _Float16* __restrict__ s0,
                                        const _Float16* __restrict__ s1,
                                        const uint4* __restrict__ w,
                                        float bias, float& Z0, float& Z1) {
    const uint4* p0 = (const uint4*)s0;
    const uint4* p1 = (const uint4*)s1;
    float a0 = 0.f, a1 = 0.f, a2 = 0.f, a3 = 0.f;
    float d0 = 0.f, d1 = 0.f, d2 = 0.f, d3 = 0.f;
    #pragma unroll
    for (int kq = 0; kq < 25; kq++) {
        uint4 vx = p0[kq];
        uint4 vy = p1[kq];
        uint4 wv = w[kq];
        a0 = fdot2f(h2bits(wv.x), h2bits(vx.x), a0);
        a1 = fdot2f(h2bits(wv.y), h2bits(vx.y), a1);
        a2 = fdot2f(h2bits(wv.z), h2bits(vx.z), a2);
        a3 = fdot2f(h2bits(wv.w), h2bits(vx.w), a3);
        d0 = fdot2f(h2bits(wv.x), h2bits(vy.x), d0);
        d1 = fdot2f(h2bits(wv.y), h2bits(vy.y), d1);
        d2 = fdot2f(h2bits(wv.z), h2bits(vy.z), d2);
        d3 = fdot2f(h2bits(wv.w), h2bits(vy.w), d3);
    }
    Z0 = (a0 + a1) + (a2 + a3) + bias;
    Z1 = (d0 + d1) + (d2 + d3) + bias;
}

// Layer-pipelined schedule: phase ph runs gemv1(ph) on waves 0-6 and
// gemv2(ph-1) on waves 8-14 concurrently (both become ready when h1(ph-1)
// is published).  26 phases instead of 50 serial GEMVs.
__global__ __launch_bounds__(NTHR, 4) void lstm_main(
    const int*   __restrict__ features,   // [B][T]
    const float* __restrict__ embedding,  // [VOCAB][H]
    const float* __restrict__ b1,         // [400]
    const float* __restrict__ b2,         // [400]
    const float* __restrict__ w_fc1,      // [100][128]
    const float* __restrict__ b_fc1,      // [128]
    const float* __restrict__ w_fc2,      // [128][2]
    const float* __restrict__ b_fc2,      // [2]
    const uint4* __restrict__ WP,         // [2][25][400] fp16 chunks
    float*       __restrict__ out)        // [B][2]
{
    __shared__ __align__(16) _Float16 xh1[Rr][200];  // [x(100) | h1(100)]
    __shared__ __align__(16) _Float16 xh2[Rr][200];  // [h1(100) | h2(100)]
    __shared__ float wred[8][2];

    const int tid  = threadIdx.x;
    const int lane = tid & 63;
    const int l    = tid >> 9;                 // 0: layer-1 half, 1: layer-2
    const int ht   = tid & 511;                // index within the half
    const int o    = (ht < 400) ? ht : 399;    // clamp for uniform loads
    const int u = o >> 2, g = o & 3;
    const int c = g * 100 + u;
    const bool owner  = (ht < 400);            // owns a real column
    const bool active = (ht < 448);            // wave-uniform: waves 0-6 / 8-14

    // This thread's layer's weight columns -> 100 VGPRs (25 x uint4).
    uint4 w[25];
    #pragma unroll
    for (int kq = 0; kq < 25; kq++)
        w[kq] = WP[(l * 25 + kq) * 400 + o];

    const float bias = (l ? b2 : b1)[c];

    const _Float16* s0 = l ? &xh2[0][0] : &xh1[0][0];
    const _Float16* s1 = l ? &xh2[1][0] : &xh1[1][0];

    // Init LDS: zero h-parts; stage x(0) as fp16.
    if (tid < 200) {
        int r = tid / 100, uu = tid % 100;
        xh1[r][100 + uu] = (_Float16)0.0f;
        xh2[r][uu]       = (_Float16)0.0f;
        xh2[r][100 + uu] = (_Float16)0.0f;
    }
    if (tid < 100) {
        int r = tid / 50, p = tid % 50;
        int f0 = features[(blockIdx.x * Rr + r) * Tn + 0];
        float2 e = *(const float2*)(embedding + (size_t)f0 * Hn + 2 * p);
        half2_t h; h.x = (_Float16)e.x; h.y = (_Float16)e.y;
        ((half2_t*)&xh1[r][0])[p] = h;
    }
    __syncthreads();

    float cst[Rr] = {0.f, 0.f};
    float hv[Rr]  = {0.f, 0.f};

    for (int ph = 0; ph <= Tn; ph++) {
        // layer-1 waves run phases 0..24 (h1(ph)); layer-2 waves run
        // phases 1..25 (h2(ph-1)).
        const bool dorun = active && (l ? (ph >= 1) : (ph < Tn));
        float2 epre = {0.f, 0.f};
        int prow = 0, pp = 0;
        if (dorun) {
            if (l == 0 && owner && g == 1 && ph + 1 < Tn) {
                // x(ph+1) prefetch: 100 g==1 owners cover 2 rows x 50 half2.
                prow = (u >= 50);
                pp   = u % 50;
                int f1 = features[(blockIdx.x * Rr + prow) * Tn + ph + 1];
                epre = *(const float2*)(embedding + (size_t)f1 * Hn + 2 * pp);
            }
            float z0, z1;
            gemv_ds(s0, s1, w, bias, z0, z1);
            hv[0] = lstm_update(z0, g, cst[0]);
            hv[1] = lstm_update(z1, g, cst[1]);
        }
        __syncthreads();                      // B1: all LDS reads done
        if (l == 0 && owner && ph < Tn) {
            if (g == 0) {                     // h1 -> recurrent + layer2 input
                xh1[0][100 + u] = (_Float16)hv[0];
                xh1[1][100 + u] = (_Float16)hv[1];
                xh2[0][u]       = (_Float16)hv[0];
                xh2[1][u]       = (_Float16)hv[1];
            }
            if (g == 1 && ph + 1 < Tn) {      // publish x(ph+1)
                half2_t h; h.x = (_Float16)epre.x; h.y = (_Float16)epre.y;
                ((half2_t*)&xh1[prow][0])[pp] = h;
            }
        }
        if (l == 1 && owner && ph >= 1 && g == 0) {   // h2(ph-1)
            xh2[0][100 + u] = (_Float16)hv[0];
            xh2[1][100 + u] = (_Float16)hv[1];
        }
        __syncthreads();                      // B2: publishes visible
    }
    // Last loop iteration's B2 already made h2(24) visible.

    // FC head: pred = (h2 @ w_fc1 + b_fc1) @ w_fc2 + b_fc2
    if (tid < Rr * FCn) {                     // 256 threads: (r,j)
        int r = tid >> 7;
        int j = tid & 127;
        float acc = b_fc1[j];
        #pragma unroll 10
        for (int uu = 0; uu < Hn; uu++)
            acc = fmaf((float)xh2[r][100 + uu], w_fc1[uu * FCn + j], acc);
        float p0 = acc * w_fc2[2 * j + 0];
        float p1 = acc * w_fc2[2 * j + 1];
        #pragma unroll
        for (int off = 32; off > 0; off >>= 1) {
            p0 += __shfl_down(p0, off, 64);
            p1 += __shfl_down(p1, off, 64);
        }
        if (lane == 0) {                      // waves 0..3
            int wv = tid >> 6;
            wred[wv][0] = p0;
            wred[wv][1] = p1;
        }
    }
    __syncthreads();
    if (tid < 4) {
        int r = tid >> 1, cls = tid & 1;
        out[(blockIdx.x * Rr + r) * 2 + cls] =
            wred[2 * r][cls] + wred[2 * r + 1][cls] + b_fc2[cls];
    }
}

extern "C" void kernel_launch(void* const* d_in, const int* in_sizes, int n_in,
                              void* d_out, int out_size, void* d_ws, size_t ws_size,
                              hipStream_t stream) {
    const int*   features  = (const int*)  d_in[0];
    const float* embedding = (const float*)d_in[1];
    const float* k1        = (const float*)d_in[2];
    const float* b1        = (const float*)d_in[3];
    const float* k2        = (const float*)d_in[4];
    const float* b2        = (const float*)d_in[5];
    const float* w_fc1     = (const float*)d_in[6];
    const float* b_fc1     = (const float*)d_in[7];
    const float* w_fc2     = (const float*)d_in[8];
    const float* b_fc2     = (const float*)d_in[9];

    uint4* WP = (uint4*)d_ws;                 // 2*25*400*16 = 320,000 B

    prep_weights<<<(20000 + 255) / 256, 256, 0, stream>>>(k1, k2, WP);
    lstm_main<<<NBLK, NTHR, 0, stream>>>(features, embedding, b1, b2,
                                         w_fc1, b_fc1, w_fc2, b_fc2,
                                         WP, (float*)d_out);
}

// Round 2
// 330.650 us; speedup vs baseline: 1.1833x; 1.1833x over previous
//
#include <hip/hip_runtime.h>
#include <cstdint>
#include <cstddef>

// Model dims
#define VOCABSZ 400001
#define Hn 100      // hidden
#define Tn 25       // timesteps
#define Bn 512      // batch
#define FCn 128
#define Rr 2        // rows (batch elems) per block
#define NBLK (Bn / Rr)   // 256 blocks -> all 256 CUs
#define NTHR 1024        // 16 waves: waves 0-6 = layer1, waves 8-14 = layer2
#define RKQ 16           // weight chunks resident in VGPRs (64 VGPRs); 25-RKQ streamed from L2

typedef _Float16 half2_t __attribute__((ext_vector_type(2)));

__device__ __forceinline__ half2_t h2bits(unsigned v) {
    union { unsigned u; half2_t h; } x; x.u = v; return x.h;
}
__device__ __forceinline__ float fdot2f(half2_t a, half2_t b, float c) {
    return __builtin_amdgcn_fdot2(a, b, c, false);   // v_dot2_f32_f16
}
__device__ __forceinline__ float sigm(float x) {
    return __fdividef(1.0f, 1.0f + __expf(-x));
}
__device__ __forceinline__ float tanh_fast(float x) {
    float e = __expf(2.0f * x);
    return __fdividef(e - 1.0f, e + 1.0f);
}

// ---------------------------------------------------------------------------
// Prep: repack k1,k2 (fp32 [200][400], columns c = g*100+u, gates i,j,f,o)
// into fp16 chunk layout WP[l][kq][o] (uint4), o = 4u+g owning column c.
// Chunk kq covers k = 8kq..8kq+7; dword j = fp16 pair (k=8kq+2j, 8kq+2j+1).
// [kq][o] order keeps streamed loads coalesced (64 lanes x consecutive o).
// ---------------------------------------------------------------------------
__global__ void prep_weights(const float* __restrict__ k1,
                             const float* __restrict__ k2,
                             uint4* __restrict__ WP) {
    int t = blockIdx.x * blockDim.x + threadIdx.x;
    if (t >= 2 * 25 * 400) return;
    int l   = t / 10000;
    int rem = t % 10000;
    int kq  = rem / 400;
    int o   = rem % 400;
    int u = o >> 2, g = o & 3;
    int c = g * 100 + u;
    const float* K = l ? k2 : k1;
    union { unsigned u32; half2_t h; } d[4];
    #pragma unroll
    for (int j = 0; j < 4; j++) {
        int k0 = 8 * kq + 2 * j;
        d[j].h.x = (_Float16)K[(k0    ) * 400 + c];
        d[j].h.y = (_Float16)K[(k0 + 1) * 400 + c];
    }
    uint4 v; v.x = d[0].u32; v.y = d[1].u32; v.z = d[2].u32; v.w = d[3].u32;
    WP[t] = v;
}

// Gate exchange within the quad (o = 4u+g) + LSTM cell update.
// All 4 lanes of the quad end up with the same c,h (redundant, cheap).
__device__ __forceinline__ float lstm_update(float z, int g, float& cst) {
    float t1 = __shfl_xor(z, 1);
    float t2 = __shfl_xor(z, 2);
    float t3 = __shfl_xor(t1, 2);
    bool g0 = (g & 1) != 0, g1 = (g & 2) != 0;
    float vi = g1 ? (g0 ? t3 : t2) : (g0 ? t1 : z);
    float vj = g1 ? (g0 ? t2 : t3) : (g0 ? z  : t1);
    float vf = g1 ? (g0 ? t1 : z ) : (g0 ? t3 : t2);
    float vo = g1 ? (g0 ? z  : t1) : (g0 ? t2 : t3);
    cst = cst * sigm(vf + 1.0f) + sigm(vi) * tanh_fast(vj);   // forget_bias=1
    return tanh_fast(cst) * sigm(vo);
}

// GEMV for both rows of this block's batch pair.  Weight chunks kq<RKQ come
// from this thread's registers; kq>=RKQ stream from WP (L2-resident, issued
// FIRST so their latency hides under the resident-half dot products).
// x/h vectors are wave-uniform broadcast ds_read_b128 (conflict-free).
__device__ __forceinline__ void gemv2(const _Float16* s0,
                                      const _Float16* s1,
                                      const uint4* wreg,
                                      const uint4* __restrict__ wp,
                                      float bias, float& Z0, float& Z1) {
    const uint4* p0 = (const uint4*)s0;
    const uint4* p1 = (const uint4*)s1;
    float a0 = 0.f, a1 = 0.f, a2 = 0.f, a3 = 0.f;
    float d0 = 0.f, d1 = 0.f, d2 = 0.f, d3 = 0.f;
    #pragma unroll
    for (int kq = RKQ; kq < 25; kq++) {       // streamed (transient regs)
        uint4 wv = wp[kq * 400];
        uint4 vx = p0[kq];
        uint4 vy = p1[kq];
        a0 = fdot2f(h2bits(wv.x), h2bits(vx.x), a0);
        a1 = fdot2f(h2bits(wv.y), h2bits(vx.y), a1);
        a2 = fdot2f(h2bits(wv.z), h2bits(vx.z), a2);
        a3 = fdot2f(h2bits(wv.w), h2bits(vx.w), a3);
        d0 = fdot2f(h2bits(wv.x), h2bits(vy.x), d0);
        d1 = fdot2f(h2bits(wv.y), h2bits(vy.y), d1);
        d2 = fdot2f(h2bits(wv.z), h2bits(vy.z), d2);
        d3 = fdot2f(h2bits(wv.w), h2bits(vy.w), d3);
    }
    #pragma unroll
    for (int kq = 0; kq < RKQ; kq++) {        // resident
        uint4 wv = wreg[kq];
        uint4 vx = p0[kq];
        uint4 vy = p1[kq];
        a0 = fdot2f(h2bits(wv.x), h2bits(vx.x), a0);
        a1 = fdot2f(h2bits(wv.y), h2bits(vx.y), a1);
        a2 = fdot2f(h2bits(wv.z), h2bits(vx.z), a2);
        a3 = fdot2f(h2bits(wv.w), h2bits(vx.w), a3);
        d0 = fdot2f(h2bits(wv.x), h2bits(vy.x), d0);
        d1 = fdot2f(h2bits(wv.y), h2bits(vy.y), d1);
        d2 = fdot2f(h2bits(wv.z), h2bits(vy.z), d2);
        d3 = fdot2f(h2bits(wv.w), h2bits(vy.w), d3);
    }
    Z0 = (a0 + a1) + (a2 + a3) + bias;
    Z1 = (d0 + d1) + (d2 + d3) + bias;
}

// Layer-pipelined schedule: phase ph runs gemv1(ph) on waves 0-6 and
// gemv2(ph-1) on waves 8-14 concurrently.  26 phases, ONE barrier each:
// reads come from xh*[ph&1], writes go to xh*[ph&1 ^ 1] (ping-pong), so
// intra-phase reads and writes touch disjoint buffers.
__global__ __launch_bounds__(NTHR, 4) void lstm_main(
    const int*   __restrict__ features,   // [B][T]
    const float* __restrict__ embedding,  // [VOCAB][H]
    const float* __restrict__ b1,         // [400]
    const float* __restrict__ b2,         // [400]
    const float* __restrict__ w_fc1,      // [100][128]
    const float* __restrict__ b_fc1,      // [128]
    const float* __restrict__ w_fc2,      // [128][2]
    const float* __restrict__ b_fc2,      // [2]
    const uint4* __restrict__ WP,         // [2][25][400] fp16 chunks
    float*       __restrict__ out)        // [B][2]
{
    __shared__ __align__(16) _Float16 xh1[2][Rr][200];  // [x(100) | h1(100)]
    __shared__ __align__(16) _Float16 xh2[2][Rr][200];  // [h1(100) | h2(100)]
    __shared__ float wred[8][2];

    const int tid  = threadIdx.x;
    const int lane = tid & 63;
    const int l    = tid >> 9;                 // 0: layer-1 half, 1: layer-2
    const int ht   = tid & 511;                // index within the half
    const int o    = (ht < 400) ? ht : 399;    // clamp for uniform loads
    const int u = o >> 2, g = o & 3;
    const int c = g * 100 + u;
    const bool owner  = (ht < 400);            // owns a real column
    const bool active = (ht < 448);            // wave-uniform: waves 0-6 / 8-14

    // This thread's layer/column weight pointer; first RKQ chunks resident.
    const uint4* wp = WP + (size_t)(l * 25) * 400 + o;
    uint4 wreg[RKQ];
    #pragma unroll
    for (int kq = 0; kq < RKQ; kq++)
        wreg[kq] = wp[kq * 400];

    const float bias = (l ? b2 : b1)[c];

    // Init: only the h-parts read before first write need zeroing.
    // ph0 reads xh1[0] (h-part must be 0); ph1 reads xh2[1] (h2-part must be 0).
    if (tid < 200) {
        int r = tid / 100, uu = tid % 100;
        xh1[0][r][100 + uu] = (_Float16)0.0f;
        xh2[1][r][100 + uu] = (_Float16)0.0f;
    }
    if (tid < 100) {                           // stage x(0) into buf 0
        int r = tid / 50, p = tid % 50;
        int f0 = features[(blockIdx.x * Rr + r) * Tn + 0];
        float2 e = *(const float2*)(embedding + (size_t)f0 * Hn + 2 * p);
        half2_t h; h.x = (_Float16)e.x; h.y = (_Float16)e.y;
        ((half2_t*)&xh1[0][r][0])[p] = h;
    }
    __syncthreads();

    float cst[Rr] = {0.f, 0.f};
    float hv[Rr]  = {0.f, 0.f};

    for (int ph = 0; ph <= Tn; ph++) {
        const int p  = ph & 1;                 // read buffer
        const int wb = p ^ 1;                  // write buffer
        // layer-1 waves run phases 0..24 (h1(ph)); layer-2 run 1..25 (h2(ph-1)).
        const bool dorun = active && (l ? (ph >= 1) : (ph < Tn));
        if (dorun) {
            float2 epre = {0.f, 0.f};
            int prow = 0, pp = 0;
            if (l == 0 && owner && g == 1 && ph + 1 < Tn) {
                // x(ph+1) prefetch: 100 g==1 owners cover 2 rows x 50 half2.
                prow = (u >= 50);
                pp   = u % 50;
                int f1 = features[(blockIdx.x * Rr + prow) * Tn + ph + 1];
                epre = *(const float2*)(embedding + (size_t)f1 * Hn + 2 * pp);
            }
            const _Float16* s0 = l ? &xh2[p][0][0] : &xh1[p][0][0];
            const _Float16* s1 = l ? &xh2[p][1][0] : &xh1[p][1][0];
            float z0, z1;
            gemv2(s0, s1, wreg, wp, bias, z0, z1);
            hv[0] = lstm_update(z0, g, cst[0]);
            hv[1] = lstm_update(z1, g, cst[1]);
            if (l == 0 && owner) {
                if (g == 0) {                  // h1 -> recurrent + layer2 input
                    xh1[wb][0][100 + u] = (_Float16)hv[0];
                    xh1[wb][1][100 + u] = (_Float16)hv[1];
                    xh2[wb][0][u]       = (_Float16)hv[0];
                    xh2[wb][1][u]       = (_Float16)hv[1];
                }
                if (g == 1 && ph + 1 < Tn) {   // publish x(ph+1)
                    half2_t h; h.x = (_Float16)epre.x; h.y = (_Float16)epre.y;
                    ((half2_t*)&xh1[wb][prow][0])[pp] = h;
                }
            }
            if (l == 1 && owner && g == 0) {   // h2(ph-1)
                xh2[wb][0][100 + u] = (_Float16)hv[0];
                xh2[wb][1][100 + u] = (_Float16)hv[1];
            }
        }
        __syncthreads();                       // writes visible; reads done
    }
    // ph=25 wrote h2(24) into xh2[0]; loop's final barrier made it visible.

    // FC head: pred = (h2 @ w_fc1 + b_fc1) @ w_fc2 + b_fc2
    if (tid < Rr * FCn) {                      // 256 threads: (r,j)
        int r = tid >> 7;
        int j = tid & 127;
        float acc = b_fc1[j];
        #pragma unroll 10
        for (int uu = 0; uu < Hn; uu++)
            acc = fmaf((float)xh2[0][r][100 + uu], w_fc1[uu * FCn + j], acc);
        float p0 = acc * w_fc2[2 * j + 0];
        float p1 = acc * w_fc2[2 * j + 1];
        #pragma unroll
        for (int off = 32; off > 0; off >>= 1) {
            p0 += __shfl_down(p0, off, 64);
            p1 += __shfl_down(p1, off, 64);
        }
        if (lane == 0) {                       // waves 0..3
            int wv = tid >> 6;
            wred[wv][0] = p0;
            wred[wv][1] = p1;
        }
    }
    __syncthreads();
    if (tid < 4) {
        int r = tid >> 1, cls = tid & 1;
        out[(blockIdx.x * Rr + r) * 2 + cls] =
            wred[2 * r][cls] + wred[2 * r + 1][cls] + b_fc2[cls];
    }
}

extern "C" void kernel_launch(void* const* d_in, const int* in_sizes, int n_in,
                              void* d_out, int out_size, void* d_ws, size_t ws_size,
                              hipStream_t stream) {
    const int*   features  = (const int*)  d_in[0];
    const float* embedding = (const float*)d_in[1];
    const float* k1        = (const float*)d_in[2];
    const float* b1        = (const float*)d_in[3];
    const float* k2        = (const float*)d_in[4];
    const float* b2        = (const float*)d_in[5];
    const float* w_fc1     = (const float*)d_in[6];
    const float* b_fc1     = (const float*)d_in[7];
    const float* w_fc2     = (const float*)d_in[8];
    const float* b_fc2     = (const float*)d_in[9];

    uint4* WP = (uint4*)d_ws;                 // 2*25*400*16 = 320,000 B

    prep_weights<<<(20000 + 255) / 256, 256, 0, stream>>>(k1, k2, WP);
    lstm_main<<<NBLK, NTHR, 0, stream>>>(features, embedding, b1, b2,
                                         w_fc1, b_fc1, w_fc2, b_fc2,
                                         WP, (float*)d_out);
}

// Round 3
// 329.521 us; speedup vs baseline: 1.1873x; 1.0034x over previous
//
#include <hip/hip_runtime.h>
#include <cstdint>
#include <cstddef>

// Model dims
#define VOCABSZ 400001
#define Hn 100      // hidden
#define Tn 25       // timesteps
#define Bn 512      // batch
#define FCn 128
#define Rr 2        // rows (batch elems) per block
#define NBLK (Bn / Rr)   // 256 blocks -> all 256 CUs
#define NTHR 1024        // 16 waves: waves 0-6 = layer1, waves 8-14 = layer2
#define RKQ 16           // weight chunks resident in VGPRs (64 VGPRs); 25-RKQ streamed from L2

typedef _Float16 half2_t __attribute__((ext_vector_type(2)));

__device__ __forceinline__ half2_t h2bits(unsigned v) {
    union { unsigned u; half2_t h; } x; x.u = v; return x.h;
}
__device__ __forceinline__ float fdot2f(half2_t a, half2_t b, float c) {
    return __builtin_amdgcn_fdot2(a, b, c, false);   // v_dot2_f32_f16
}
__device__ __forceinline__ float sigm(float x) {
    return __fdividef(1.0f, 1.0f + __expf(-x));
}
__device__ __forceinline__ float tanh_fast(float x) {
    float e = __expf(2.0f * x);
    return __fdividef(e - 1.0f, e + 1.0f);
}

// ---------------------------------------------------------------------------
// Prep: repack k1,k2 (fp32 [200][400], columns c = g*100+u, gates i,j,f,o)
// into fp16 chunk layout WP[l][kq][o] (uint4), o = 4u+g owning column c.
// Chunk kq covers k = 8kq..8kq+7; dword j = fp16 pair (k=8kq+2j, 8kq+2j+1).
// [kq][o] order keeps streamed loads coalesced (64 lanes x consecutive o).
// ---------------------------------------------------------------------------
__global__ void prep_weights(const float* __restrict__ k1,
                             const float* __restrict__ k2,
                             uint4* __restrict__ WP) {
    int t = blockIdx.x * blockDim.x + threadIdx.x;
    if (t >= 2 * 25 * 400) return;
    int l   = t / 10000;
    int rem = t % 10000;
    int kq  = rem / 400;
    int o   = rem % 400;
    int u = o >> 2, g = o & 3;
    int c = g * 100 + u;
    const float* K = l ? k2 : k1;
    union { unsigned u32; half2_t h; } d[4];
    #pragma unroll
    for (int j = 0; j < 4; j++) {
        int k0 = 8 * kq + 2 * j;
        d[j].h.x = (_Float16)K[(k0    ) * 400 + c];
        d[j].h.y = (_Float16)K[(k0 + 1) * 400 + c];
    }
    uint4 v; v.x = d[0].u32; v.y = d[1].u32; v.z = d[2].u32; v.w = d[3].u32;
    WP[t] = v;
}

// Gate exchange within the quad (o = 4u+g) + LSTM cell update.
// All 4 lanes of the quad end up with the same c,h (redundant, cheap).
__device__ __forceinline__ float lstm_update(float z, int g, float& cst) {
    float t1 = __shfl_xor(z, 1);
    float t2 = __shfl_xor(z, 2);
    float t3 = __shfl_xor(t1, 2);
    bool g0 = (g & 1) != 0, g1 = (g & 2) != 0;
    float vi = g1 ? (g0 ? t3 : t2) : (g0 ? t1 : z);
    float vj = g1 ? (g0 ? t2 : t3) : (g0 ? z  : t1);
    float vf = g1 ? (g0 ? t1 : z ) : (g0 ? t3 : t2);
    float vo = g1 ? (g0 ? z  : t1) : (g0 ? t2 : t3);
    cst = cst * sigm(vf + 1.0f) + sigm(vi) * tanh_fast(vj);   // forget_bias=1
    return tanh_fast(cst) * sigm(vo);
}

// GEMV for both rows of this block's batch pair.  Weight chunks kq<RKQ come
// from this thread's registers; kq>=RKQ stream from WP (L2-resident, issued
// FIRST so their latency hides under the resident-half dot products).
// x/h vectors are wave-uniform broadcast ds_read_b128 (conflict-free).
__device__ __forceinline__ void gemv2(const _Float16* s0,
                                      const _Float16* s1,
                                      const uint4* wreg,
                                      const uint4* __restrict__ wp,
                                      float bias, float& Z0, float& Z1) {
    const uint4* p0 = (const uint4*)s0;
    const uint4* p1 = (const uint4*)s1;
    float a0 = 0.f, a1 = 0.f, a2 = 0.f, a3 = 0.f;
    float d0 = 0.f, d1 = 0.f, d2 = 0.f, d3 = 0.f;
    #pragma unroll
    for (int kq = RKQ; kq < 25; kq++) {       // streamed (transient regs)
        uint4 wv = wp[kq * 400];
        uint4 vx = p0[kq];
        uint4 vy = p1[kq];
        a0 = fdot2f(h2bits(wv.x), h2bits(vx.x), a0);
        a1 = fdot2f(h2bits(wv.y), h2bits(vx.y), a1);
        a2 = fdot2f(h2bits(wv.z), h2bits(vx.z), a2);
        a3 = fdot2f(h2bits(wv.w), h2bits(vx.w), a3);
        d0 = fdot2f(h2bits(wv.x), h2bits(vy.x), d0);
        d1 = fdot2f(h2bits(wv.y), h2bits(vy.y), d1);
        d2 = fdot2f(h2bits(wv.z), h2bits(vy.z), d2);
        d3 = fdot2f(h2bits(wv.w), h2bits(vy.w), d3);
    }
    #pragma unroll
    for (int kq = 0; kq < RKQ; kq++) {        // resident
        uint4 wv = wreg[kq];
        uint4 vx = p0[kq];
        uint4 vy = p1[kq];
        a0 = fdot2f(h2bits(wv.x), h2bits(vx.x), a0);
        a1 = fdot2f(h2bits(wv.y), h2bits(vx.y), a1);
        a2 = fdot2f(h2bits(wv.z), h2bits(vx.z), a2);
        a3 = fdot2f(h2bits(wv.w), h2bits(vx.w), a3);
        d0 = fdot2f(h2bits(wv.x), h2bits(vy.x), d0);
        d1 = fdot2f(h2bits(wv.y), h2bits(vy.y), d1);
        d2 = fdot2f(h2bits(wv.z), h2bits(vy.z), d2);
        d3 = fdot2f(h2bits(wv.w), h2bits(vy.w), d3);
    }
    Z0 = (a0 + a1) + (a2 + a3) + bias;
    Z1 = (d0 + d1) + (d2 + d3) + bias;
}

// Layer-pipelined schedule: phase ph runs gemv1(ph) on waves 0-6 and
// gemv2(ph-1) on waves 8-14 concurrently.  26 phases, ONE barrier each:
// reads come from xh*[ph&1], writes go to xh*[ph&1 ^ 1] (ping-pong), so
// intra-phase reads and writes touch disjoint buffers.
//
// __launch_bounds__ 2nd arg: hipcc treats it CUDA-style as min BLOCKS/CU.
//   (1024,4) -> 64 waves/CU clamped to 32 -> 8 waves/SIMD -> 64-VGPR cap
//   -> wreg spilled to scratch (R1: 77MB, R2: 10MB scratch traffic).
//   (1024,1) -> 16 waves/CU -> 4 waves/SIMD -> 128-VGPR cap: wreg fits.
__global__ __launch_bounds__(NTHR, 1) void lstm_main(
    const int*   __restrict__ features,   // [B][T]
    const float* __restrict__ embedding,  // [VOCAB][H]
    const float* __restrict__ b1,         // [400]
    const float* __restrict__ b2,         // [400]
    const float* __restrict__ w_fc1,      // [100][128]
    const float* __restrict__ b_fc1,      // [128]
    const float* __restrict__ w_fc2,      // [128][2]
    const float* __restrict__ b_fc2,      // [2]
    const uint4* __restrict__ WP,         // [2][25][400] fp16 chunks
    float*       __restrict__ out)        // [B][2]
{
    __shared__ __align__(16) _Float16 xh1[2][Rr][200];  // [x(100) | h1(100)]
    __shared__ __align__(16) _Float16 xh2[2][Rr][200];  // [h1(100) | h2(100)]
    __shared__ float wred[8][2];

    const int tid  = threadIdx.x;
    const int lane = tid & 63;
    const int l    = tid >> 9;                 // 0: layer-1 half, 1: layer-2
    const int ht   = tid & 511;                // index within the half
    const int o    = (ht < 400) ? ht : 399;    // clamp for uniform loads
    const int u = o >> 2, g = o & 3;
    const int c = g * 100 + u;
    const bool owner  = (ht < 400);            // owns a real column
    const bool active = (ht < 448);            // wave-uniform: waves 0-6 / 8-14

    // This thread's layer/column weight pointer; first RKQ chunks resident.
    const uint4* wp = WP + (size_t)(l * 25) * 400 + o;
    uint4 wreg[RKQ];
    #pragma unroll
    for (int kq = 0; kq < RKQ; kq++)
        wreg[kq] = wp[kq * 400];

    const float bias = (l ? b2 : b1)[c];

    // Init: only the h-parts read before first write need zeroing.
    // ph0 reads xh1[0] (h-part must be 0); ph1 reads xh2[1] (h2-part must be 0).
    if (tid < 200) {
        int r = tid / 100, uu = tid % 100;
        xh1[0][r][100 + uu] = (_Float16)0.0f;
        xh2[1][r][100 + uu] = (_Float16)0.0f;
    }
    if (tid < 100) {                           // stage x(0) into buf 0
        int r = tid / 50, p = tid % 50;
        int f0 = features[(blockIdx.x * Rr + r) * Tn + 0];
        float2 e = *(const float2*)(embedding + (size_t)f0 * Hn + 2 * p);
        half2_t h; h.x = (_Float16)e.x; h.y = (_Float16)e.y;
        ((half2_t*)&xh1[0][r][0])[p] = h;
    }
    __syncthreads();

    float cst[Rr] = {0.f, 0.f};
    float hv[Rr]  = {0.f, 0.f};

    for (int ph = 0; ph <= Tn; ph++) {
        const int p  = ph & 1;                 // read buffer
        const int wb = p ^ 1;                  // write buffer
        // layer-1 waves run phases 0..24 (h1(ph)); layer-2 run 1..25 (h2(ph-1)).
        const bool dorun = active && (l ? (ph >= 1) : (ph < Tn));
        if (dorun) {
            float2 epre = {0.f, 0.f};
            int prow = 0, pp = 0;
            if (l == 0 && owner && g == 1 && ph + 1 < Tn) {
                // x(ph+1) prefetch: 100 g==1 owners cover 2 rows x 50 half2.
                prow = (u >= 50);
                pp   = u % 50;
                int f1 = features[(blockIdx.x * Rr + prow) * Tn + ph + 1];
                epre = *(const float2*)(embedding + (size_t)f1 * Hn + 2 * pp);
            }
            const _Float16* s0 = l ? &xh2[p][0][0] : &xh1[p][0][0];
            const _Float16* s1 = l ? &xh2[p][1][0] : &xh1[p][1][0];
            float z0, z1;
            gemv2(s0, s1, wreg, wp, bias, z0, z1);
            hv[0] = lstm_update(z0, g, cst[0]);
            hv[1] = lstm_update(z1, g, cst[1]);
            if (l == 0 && owner) {
                if (g == 0) {                  // h1 -> recurrent + layer2 input
                    xh1[wb][0][100 + u] = (_Float16)hv[0];
                    xh1[wb][1][100 + u] = (_Float16)hv[1];
                    xh2[wb][0][u]       = (_Float16)hv[0];
                    xh2[wb][1][u]       = (_Float16)hv[1];
                }
                if (g == 1 && ph + 1 < Tn) {   // publish x(ph+1)
                    half2_t h; h.x = (_Float16)epre.x; h.y = (_Float16)epre.y;
                    ((half2_t*)&xh1[wb][prow][0])[pp] = h;
                }
            }
            if (l == 1 && owner && g == 0) {   // h2(ph-1)
                xh2[wb][0][100 + u] = (_Float16)hv[0];
                xh2[wb][1][100 + u] = (_Float16)hv[1];
            }
        }
        __syncthreads();                       // writes visible; reads done
    }
    // ph=25 wrote h2(24) into xh2[0]; loop's final barrier made it visible.

    // FC head: pred = (h2 @ w_fc1 + b_fc1) @ w_fc2 + b_fc2
    if (tid < Rr * FCn) {                      // 256 threads: (r,j)
        int r = tid >> 7;
        int j = tid & 127;
        float acc = b_fc1[j];
        #pragma unroll 10
        for (int uu = 0; uu < Hn; uu++)
            acc = fmaf((float)xh2[0][r][100 + uu], w_fc1[uu * FCn + j], acc);
        float p0 = acc * w_fc2[2 * j + 0];
        float p1 = acc * w_fc2[2 * j + 1];
        #pragma unroll
        for (int off = 32; off > 0; off >>= 1) {
            p0 += __shfl_down(p0, off, 64);
            p1 += __shfl_down(p1, off, 64);
        }
        if (lane == 0) {                       // waves 0..3
            int wv = tid >> 6;
            wred[wv][0] = p0;
            wred[wv][1] = p1;
        }
    }
    __syncthreads();
    if (tid < 4) {
        int r = tid >> 1, cls = tid & 1;
        out[(blockIdx.x * Rr + r) * 2 + cls] =
            wred[2 * r][cls] + wred[2 * r + 1][cls] + b_fc2[cls];
    }
}

extern "C" void kernel_launch(void* const* d_in, const int* in_sizes, int n_in,
                              void* d_out, int out_size, void* d_ws, size_t ws_size,
                              hipStream_t stream) {
    const int*   features  = (const int*)  d_in[0];
    const float* embedding = (const float*)d_in[1];
    const float* k1        = (const float*)d_in[2];
    const float* b1        = (const float*)d_in[3];
    const float* k2        = (const float*)d_in[4];
    const float* b2        = (const float*)d_in[5];
    const float* w_fc1     = (const float*)d_in[6];
    const float* b_fc1     = (const float*)d_in[7];
    const float* w_fc2     = (const float*)d_in[8];
    const float* b_fc2     = (const float*)d_in[9];

    uint4* WP = (uint4*)d_ws;                 // 2*25*400*16 = 320,000 B

    prep_weights<<<(20000 + 255) / 256, 256, 0, stream>>>(k1, k2, WP);
    lstm_main<<<NBLK, NTHR, 0, stream>>>(features, embedding, b1, b2,
                                         w_fc1, b_fc1, w_fc2, b_fc2,
                                         WP, (float*)d_out);
}

// Round 5
// 325.829 us; speedup vs baseline: 1.2008x; 1.0113x over previous
//
#include <hip/hip_runtime.h>
#include <cstdint>
#include <cstddef>

// Model dims
#define VOCABSZ 400001
#define Hn 100      // hidden
#define Tn 25       // timesteps
#define Bn 512      // batch
#define FCn 128
#define Rr 2        // rows (batch elems) per block
#define NBLK (Bn / Rr)   // 256 blocks -> all 256 CUs
#define NTHR 1024        // 16 waves: waves 0-6 = layer1, waves 8-14 = layer2

// Weight residency plan (hipcc pins 1024-thr blocks at 64 VGPRs -- R1/R2/R3
// evidence: VGPR_Count=64 regardless of __launch_bounds__; wreg[16] spilled):
//   kq 0..5         : VGPR  (wreg[6] = 24 regs, fits the 64-reg budget)
//   layer1 kq 6..24 : LDS  (19 chunks)
//   layer2 kq 6..9  : LDS  ( 4 chunks)
//   layer2 kq 10..24: streamed from L2 (15 chunks, 96 KB/phase)
// LDS budget: 23*400*16 = 147,200 B weights + 3,264 B state = 150,464 B
// (9.4 KB headroom under the 160 KiB HW limit -- R4's 156.9 KB try may have
// tripped a runtime reservation; keep margin).
#define RKQ   6
#define L1LDS 19
#define L2LDS 4
#define WLCH  (L1LDS + L2LDS)    // 23 chunks in LDS = 147,200 B

typedef _Float16 half2_t __attribute__((ext_vector_type(2)));

__device__ __forceinline__ half2_t h2bits(unsigned v) {
    union { unsigned u; half2_t h; } x; x.u = v; return x.h;
}
__device__ __forceinline__ float fdot2f(half2_t a, half2_t b, float c) {
    return __builtin_amdgcn_fdot2(a, b, c, false);   // v_dot2_f32_f16
}
__device__ __forceinline__ float sigm(float x) {
    return __fdividef(1.0f, 1.0f + __expf(-x));
}
__device__ __forceinline__ float tanh_fast(float x) {
    float e = __expf(2.0f * x);
    return __fdividef(e - 1.0f, e + 1.0f);
}

// ---------------------------------------------------------------------------
// Prep: repack k1,k2 (fp32 [200][400], columns c = g*100+u, gates i,j,f,o)
// into fp16 chunk layout WP[l][kq][o] (uint4), o = 4u+g owning column c.
// Chunk kq covers k = 8kq..8kq+7; dword j = fp16 pair (k=8kq+2j, 8kq+2j+1).
// [kq][o] order keeps streamed loads coalesced (64 lanes x consecutive o).
// ---------------------------------------------------------------------------
__global__ void prep_weights(const float* __restrict__ k1,
                             const float* __restrict__ k2,
                             uint4* __restrict__ WP) {
    int t = blockIdx.x * blockDim.x + threadIdx.x;
    if (t >= 2 * 25 * 400) return;
    int l   = t / 10000;
    int rem = t % 10000;
    int kq  = rem / 400;
    int o   = rem % 400;
    int u = o >> 2, g = o & 3;
    int c = g * 100 + u;
    const float* K = l ? k2 : k1;
    union { unsigned u32; half2_t h; } d[4];
    #pragma unroll
    for (int j = 0; j < 4; j++) {
        int k0 = 8 * kq + 2 * j;
        d[j].h.x = (_Float16)K[(k0    ) * 400 + c];
        d[j].h.y = (_Float16)K[(k0 + 1) * 400 + c];
    }
    uint4 v; v.x = d[0].u32; v.y = d[1].u32; v.z = d[2].u32; v.w = d[3].u32;
    WP[t] = v;
}

// Gate exchange within the quad (o = 4u+g) + LSTM cell update.
// All 4 lanes of the quad end up with the same c,h (redundant, cheap).
__device__ __forceinline__ float lstm_update(float z, int g, float& cst) {
    float t1 = __shfl_xor(z, 1);
    float t2 = __shfl_xor(z, 2);
    float t3 = __shfl_xor(t1, 2);
    bool g0 = (g & 1) != 0, g1 = (g & 2) != 0;
    float vi = g1 ? (g0 ? t3 : t2) : (g0 ? t1 : z);
    float vj = g1 ? (g0 ? t2 : t3) : (g0 ? z  : t1);
    float vf = g1 ? (g0 ? t1 : z ) : (g0 ? t3 : t2);
    float vo = g1 ? (g0 ? z  : t1) : (g0 ? t2 : t3);
    cst = cst * sigm(vf + 1.0f) + sigm(vi) * tanh_fast(vj);   // forget_bias=1
    return tanh_fast(cst) * sigm(vo);
}

// GEMV for both rows of this block's batch pair.
//   kq 0..5          : wreg (VGPR)
//   kq 6..6+NLDS-1   : lw   (LDS, per-lane contiguous uint4 -> conflict-free)
//   kq 6+NLDS..24    : gw   (global, L2-resident; issued FIRST for latency)
// x/h vectors p0/p1 are wave-uniform broadcast ds_read_b128.
template<int NG>
__device__ __forceinline__ void gemv(const uint4* p0, const uint4* p1,
                                     const uint4* wreg, const uint4* lw,
                                     const uint4* __restrict__ gw,
                                     float bias, float& Z0, float& Z1) {
    constexpr int NLDS = 19 - NG;
    float a0 = 0.f, a1 = 0.f, a2 = 0.f, a3 = 0.f;
    float d0 = 0.f, d1 = 0.f, d2 = 0.f, d3 = 0.f;
    #pragma unroll
    for (int t = 0; t < NG; t++) {            // L2-streamed (issued first)
        uint4 wv = gw[t * 400];
        uint4 vx = p0[RKQ + NLDS + t];
        uint4 vy = p1[RKQ + NLDS + t];
        a0 = fdot2f(h2bits(wv.x), h2bits(vx.x), a0);
        a1 = fdot2f(h2bits(wv.y), h2bits(vx.y), a1);
        a2 = fdot2f(h2bits(wv.z), h2bits(vx.z), a2);
        a3 = fdot2f(h2bits(wv.w), h2bits(vx.w), a3);
        d0 = fdot2f(h2bits(wv.x), h2bits(vy.x), d0);
        d1 = fdot2f(h2bits(wv.y), h2bits(vy.y), d1);
        d2 = fdot2f(h2bits(wv.z), h2bits(vy.z), d2);
        d3 = fdot2f(h2bits(wv.w), h2bits(vy.w), d3);
    }
    #pragma unroll
    for (int t = 0; t < NLDS; t++) {          // LDS-resident
        uint4 wv = lw[t * 400];
        uint4 vx = p0[RKQ + t];
        uint4 vy = p1[RKQ + t];
        a0 = fdot2f(h2bits(wv.x), h2bits(vx.x), a0);
        a1 = fdot2f(h2bits(wv.y), h2bits(vx.y), a1);
        a2 = fdot2f(h2bits(wv.z), h2bits(vx.z), a2);
        a3 = fdot2f(h2bits(wv.w), h2bits(vx.w), a3);
        d0 = fdot2f(h2bits(wv.x), h2bits(vy.x), d0);
        d1 = fdot2f(h2bits(wv.y), h2bits(vy.y), d1);
        d2 = fdot2f(h2bits(wv.z), h2bits(vy.z), d2);
        d3 = fdot2f(h2bits(wv.w), h2bits(vy.w), d3);
    }
    #pragma unroll
    for (int kq = 0; kq < RKQ; kq++) {        // VGPR-resident
        uint4 wv = wreg[kq];
        uint4 vx = p0[kq];
        uint4 vy = p1[kq];
        a0 = fdot2f(h2bits(wv.x), h2bits(vx.x), a0);
        a1 = fdot2f(h2bits(wv.y), h2bits(vx.y), a1);
        a2 = fdot2f(h2bits(wv.z), h2bits(vx.z), a2);
        a3 = fdot2f(h2bits(wv.w), h2bits(vx.w), a3);
        d0 = fdot2f(h2bits(wv.x), h2bits(vy.x), d0);
        d1 = fdot2f(h2bits(wv.y), h2bits(vy.y), d1);
        d2 = fdot2f(h2bits(wv.z), h2bits(vy.z), d2);
        d3 = fdot2f(h2bits(wv.w), h2bits(vy.w), d3);
    }
    Z0 = (a0 + a1) + (a2 + a3) + bias;
    Z1 = (d0 + d1) + (d2 + d3) + bias;
}

// Layer-pipelined schedule: phase ph runs gemv1(ph) on waves 0-6 and
// gemv2(ph-1) on waves 8-14 concurrently.  26 phases, ONE barrier each:
// reads come from xh*[ph&1], writes go to xh*[ph&1 ^ 1] (ping-pong).
__global__ __launch_bounds__(NTHR, 1) void lstm_main(
    const int*   __restrict__ features,   // [B][T]
    const float* __restrict__ embedding,  // [VOCAB][H]
    const float* __restrict__ b1,         // [400]
    const float* __restrict__ b2,         // [400]
    const float* __restrict__ w_fc1,      // [100][128]
    const float* __restrict__ b_fc1,      // [128]
    const float* __restrict__ w_fc2,      // [128][2]
    const float* __restrict__ b_fc2,      // [2]
    const uint4* __restrict__ WP,         // [2][25][400] fp16 chunks
    float*       __restrict__ out)        // [B][2]
{
    // 147,200 + 1,600 + 1,600 + 64 = 150,464 B  (<= 160 KiB/CU, 9.4K margin)
    __shared__ __align__(16) uint4    WL[WLCH * 400];
    __shared__ __align__(16) _Float16 xh1[2][Rr][200];  // [x(100) | h1(100)]
    __shared__ __align__(16) _Float16 xh2[2][Rr][200];  // [h1(100) | h2(100)]
    __shared__ float wred[8][2];

    const int tid  = threadIdx.x;
    const int lane = tid & 63;
    const int l    = tid >> 9;                 // 0: layer-1 half, 1: layer-2
    const int ht   = tid & 511;                // index within the half
    const int o    = (ht < 400) ? ht : 399;    // clamp for uniform loads
    const int u = o >> 2, g = o & 3;
    const int c = g * 100 + u;
    const bool owner  = (ht < 400);            // owns a real column
    const bool active = (ht < 448);            // wave-uniform: waves 0-6 / 8-14

    const uint4* wp = WP + (size_t)(l * 25) * 400 + o;
    uint4 wreg[RKQ];
    #pragma unroll
    for (int kq = 0; kq < RKQ; kq++)
        wreg[kq] = wp[kq * 400];

    // This thread's LDS weight base: layer1 -> chunks [0,19), layer2 -> [19,23).
    const uint4* lw = &WL[(l ? L1LDS * 400 : 0) + o];
    const uint4* gw = wp + (RKQ + L2LDS) * 400;   // layer2 streamed kq 10..24

    const float bias = (l ? b2 : b1)[c];

    // Stage LDS weights: WL[i][oo] with i<19 -> (l=0, kq=6+i),
    //                                 i>=19 -> (l=1, kq=6+(i-19)).
    for (int idx = tid; idx < WLCH * 400; idx += NTHR) {
        int i  = idx / 400;
        int oo = idx - i * 400;
        int ll = (i < L1LDS) ? 0 : 1;
        int kk = (i < L1LDS) ? (RKQ + i) : (RKQ + i - L1LDS);
        WL[idx] = WP[(ll * 25 + kk) * 400 + oo];
    }

    // Init: ph0 reads xh1[0] (h-part must be 0); ph1 reads xh2[1] (h2-part 0).
    if (tid < 200) {
        int r = tid / 100, uu = tid % 100;
        xh1[0][r][100 + uu] = (_Float16)0.0f;
        xh2[1][r][100 + uu] = (_Float16)0.0f;
    }
    if (tid < 100) {                           // stage x(0) into buf 0
        int r = tid / 50, p = tid % 50;
        int f0 = features[(blockIdx.x * Rr + r) * Tn + 0];
        float2 e = *(const float2*)(embedding + (size_t)f0 * Hn + 2 * p);
        half2_t h; h.x = (_Float16)e.x; h.y = (_Float16)e.y;
        ((half2_t*)&xh1[0][r][0])[p] = h;
    }
    __syncthreads();

    float cst[Rr] = {0.f, 0.f};
    float hv[Rr]  = {0.f, 0.f};

    for (int ph = 0; ph <= Tn; ph++) {
        const int p  = ph & 1;                 // read buffer
        const int wb = p ^ 1;                  // write buffer
        // layer-1 waves run phases 0..24 (h1(ph)); layer-2 run 1..25 (h2(ph-1)).
        const bool dorun = active && (l ? (ph >= 1) : (ph < Tn));
        if (dorun) {
            float2 epre = {0.f, 0.f};
            int prow = 0, pp = 0;
            if (l == 0 && owner && g == 1 && ph + 1 < Tn) {
                // x(ph+1) prefetch: 100 g==1 owners cover 2 rows x 50 half2.
                prow = (u >= 50);
                pp   = u % 50;
                int f1 = features[(blockIdx.x * Rr + prow) * Tn + ph + 1];
                epre = *(const float2*)(embedding + (size_t)f1 * Hn + 2 * pp);
            }
            const uint4* p0 = (const uint4*)(l ? &xh2[p][0][0] : &xh1[p][0][0]);
            const uint4* p1 = (const uint4*)(l ? &xh2[p][1][0] : &xh1[p][1][0]);
            float z0, z1;
            if (l == 0) gemv<0> (p0, p1, wreg, lw, gw, bias, z0, z1);
            else        gemv<15>(p0, p1, wreg, lw, gw, bias, z0, z1);
            hv[0] = lstm_update(z0, g, cst[0]);
            hv[1] = lstm_update(z1, g, cst[1]);
            if (l == 0 && owner) {
                if (g == 0) {                  // h1 -> recurrent + layer2 input
                    xh1[wb][0][100 + u] = (_Float16)hv[0];
                    xh1[wb][1][100 + u] = (_Float16)hv[1];
                    xh2[wb][0][u]       = (_Float16)hv[0];
                    xh2[wb][1][u]       = (_Float16)hv[1];
                }
                if (g == 1 && ph + 1 < Tn) {   // publish x(ph+1)
                    half2_t h; h.x = (_Float16)epre.x; h.y = (_Float16)epre.y;
                    ((half2_t*)&xh1[wb][prow][0])[pp] = h;
                }
            }
            if (l == 1 && owner && g == 0) {   // h2(ph-1)
                xh2[wb][0][100 + u] = (_Float16)hv[0];
                xh2[wb][1][100 + u] = (_Float16)hv[1];
            }
        }
        __syncthreads();                       // writes visible; reads done
    }
    // ph=25 wrote h2(24) into xh2[0]; loop's final barrier made it visible.

    // FC head: pred = (h2 @ w_fc1 + b_fc1) @ w_fc2 + b_fc2
    if (tid < Rr * FCn) {                      // 256 threads: (r,j)
        int r = tid >> 7;
        int j = tid & 127;
        float acc = b_fc1[j];
        #pragma unroll 10
        for (int uu = 0; uu < Hn; uu++)
            acc = fmaf((float)xh2[0][r][100 + uu], w_fc1[uu * FCn + j], acc);
        float p0 = acc * w_fc2[2 * j + 0];
        float p1 = acc * w_fc2[2 * j + 1];
        #pragma unroll
        for (int off = 32; off > 0; off >>= 1) {
            p0 += __shfl_down(p0, off, 64);
            p1 += __shfl_down(p1, off, 64);
        }
        if (lane == 0) {                       // waves 0..3
            int wv = tid >> 6;
            wred[wv][0] = p0;
            wred[wv][1] = p1;
        }
    }
    __syncthreads();
    if (tid < 4) {
        int r = tid >> 1, cls = tid & 1;
        out[(blockIdx.x * Rr + r) * 2 + cls] =
            wred[2 * r][cls] + wred[2 * r + 1][cls] + b_fc2[cls];
    }
}

extern "C" void kernel_launch(void* const* d_in, const int* in_sizes, int n_in,
                              void* d_out, int out_size, void* d_ws, size_t ws_size,
                              hipStream_t stream) {
    const int*   features  = (const int*)  d_in[0];
    const float* embedding = (const float*)d_in[1];
    const float* k1        = (const float*)d_in[2];
    const float* b1        = (const float*)d_in[3];
    const float* k2        = (const float*)d_in[4];
    const float* b2        = (const float*)d_in[5];
    const float* w_fc1     = (const float*)d_in[6];
    const float* b_fc1     = (const float*)d_in[7];
    const float* w_fc2     = (const float*)d_in[8];
    const float* b_fc2     = (const float*)d_in[9];

    uint4* WP = (uint4*)d_ws;                 // 2*25*400*16 = 320,000 B

    prep_weights<<<(20000 + 255) / 256, 256, 0, stream>>>(k1, k2, WP);
    lstm_main<<<NBLK, NTHR, 0, stream>>>(features, embedding, b1, b2,
                                         w_fc1, b_fc1, w_fc2, b_fc2,
                                         WP, (float*)d_out);
}